// Round 11
// baseline (175.335 us; speedup 1.0000x reference)
//
#include <hip/hip_runtime.h>
#include <hip/hip_bf16.h>

typedef __attribute__((ext_vector_type(8))) short  s16x8;   // 8 x bf16
typedef __attribute__((ext_vector_type(4))) short  s16x4;
typedef __attribute__((ext_vector_type(4))) float  f32x4;

#define T_LEN 50000
#define S_LEN 168
#define W_IN  336
#define O_OUT 48
#define N_ROWS (T_LEN - W_IN - O_OUT + 1)   // 49617
#define N_PAD  49664                        // 776 * 64
#define NBLK   (N_PAD / 64)                 // 776

__device__ inline short f2bf(float f) {
    union { float f; unsigned u; } v; v.f = f;
    unsigned u = v.u;
    unsigned r = u + 0x7fffu + ((u >> 16) & 1u);   // RNE
    return (short)(r >> 16);
}

__device__ inline int bfpk(float lo, float hi) {   // 2xf32 -> packed 2xbf16 (RNE)
    float2 f2; f2.x = lo; f2.y = hi;
    __hip_bfloat162 h = __float22bfloat162_rn(f2);
    int r; __builtin_memcpy(&r, &h, 4);
    return r;
}

__device__ inline float readlane_f(float v, int l) {
    return __int_as_float(__builtin_amdgcn_readlane(__float_as_int(v), l));
}

__device__ inline float fast_tanh(float v) {
    float e = __expf(2.f * v);
    return 1.f - 2.f * __builtin_amdgcn_rcpf(e + 1.f);
}

// ---- pre-convert W1 -> W1T bf16 [352][352], W2 -> W2T [48][360], S1[j] = colsum(W1) -------
__global__ void k_preconvert(const float* __restrict__ W1, const float* __restrict__ W2,
                             short* __restrict__ W1T, short* __restrict__ W2T,
                             float* __restrict__ S1) {
    int idx = blockIdx.x * 256 + threadIdx.x;
    const int n1 = 352 * 352;
    const int n2 = n1 + 48 * 360;
    if (idx < n1) {
        int j = idx / 352, k = idx % 352;
        W1T[idx] = (j < 336 && k < 336) ? f2bf(W1[k * 336 + j]) : (short)0;
    } else if (idx < n2) {
        int i2 = idx - n1;
        int o = i2 / 360, k = i2 % 360;
        W2T[i2] = (k < 336) ? f2bf(W2[k * 48 + o]) : (short)0;
    } else if (idx < n2 + 352) {
        int j = idx - n2;
        float s = 0.f;
        if (j < 336)
            for (int k = 0; k < 336; ++k) s += W1[k * 336 + j];
        S1[j] = s;
    }
}

// ---------------- scan: packed lw stores, row_bcast DPP scan, peeled clamp -----------------
#define DPP_FMA(q_, CTRL, W, RM) { \
    int t_ = __builtin_amdgcn_update_dpp(0, __float_as_int(q_), (CTRL), (RM), 0xf, true); \
    q_ = fmaf((W), __int_as_float(t_), q_); }

__global__ void k_scan(const float* __restrict__ x, const float* __restrict__ level_sc,
                       const float* __restrict__ seas_sc, const float* __restrict__ init_seas,
                       float* __restrict__ lw, float* __restrict__ seasinit) {
    __shared__ float ring[256];      // ring[s & 255] = seas(s)
    int lane = threadIdx.x;          // 64 threads, 1 wave
    float a = 1.f / (1.f + expf(-level_sc[0]));
    float g = 1.f / (1.f + expf(-seas_sc[0]));
    float om = 1.f - a, omg = 1.f - g;

    for (int t = lane; t < 256; t += 64) {
        float s = 1.f;
        if (t <= S_LEN) { s = expf(init_seas[t < S_LEN ? t : 0]); seasinit[t] = s; }
        ring[t] = s;
    }
    float lpv = x[0] / expf(init_seas[0]);
    if (lane == 0) { lw[0] = lpv; lw[1] = 1.f; }
    __syncthreads();

    float om1 = om, om2v = om1 * om1, om4 = om2v * om2v, om8 = om4 * om4;
    float pl    = powf(om, (float)(lane + 1));
    float fpre  = powf(om, (float)((lane & 15) + 1));
    float fpre2 = powf(om, (float)((lane & 31) + 1));

#define SCAN(QOUT, XV, RSV) { \
    float q_ = a * (XV) * (RSV); \
    DPP_FMA(q_, 0x111, om1,  0xf); \
    DPP_FMA(q_, 0x112, om2v, 0xf); \
    DPP_FMA(q_, 0x114, om4,  0xf); \
    DPP_FMA(q_, 0x118, om8,  0xf); \
    DPP_FMA(q_, 0x142, fpre,  0xa); \
    DPP_FMA(q_, 0x143, fpre2, 0xc); \
    QOUT = q_; }

#define XLOAD(I) float xr##I = x[1 + 64 * I + lane];
    XLOAD(0) XLOAD(1) XLOAD(2) XLOAD(3) XLOAD(4) XLOAD(5) XLOAD(6) XLOAD(7)
    XLOAD(8) XLOAD(9) XLOAD(10) XLOAD(11) XLOAD(12) XLOAD(13) XLOAD(14) XLOAD(15)
#undef XLOAD

    float sA0 = ring[1 + lane];
    float Qcur; SCAN(Qcur, xr0, __builtin_amdgcn_rcpf(sA0));
    float sW = sA0;
    float ldsA = ring[65 + lane];
    float ldsB;
    int ib = 1;

#define BODY(R, RN, LIN, LOUT, CLAMP) { \
    float lvl = fmaf(pl, lpv, Qcur); \
    lpv = readlane_f(lvl, 63); \
    float w_ = fmaf(omg, sW, (g * xr##R) * __builtin_amdgcn_rcpf(lvl)); \
    float2 pk_; pk_.x = lvl; pk_.y = w_; \
    *(float2*)&lw[2 * (ib + lane)] = pk_; \
    ring[(ib + S_LEN + lane) & 255] = w_; \
    LOUT = ring[(ib + 128 + lane) & 255]; \
    float Qn_; SCAN(Qn_, xr##RN, __builtin_amdgcn_rcpf(LIN)); \
    int pidx = ib + 1024 + lane; \
    if (CLAMP) pidx = pidx > (T_LEN - 1) ? (T_LEN - 1) : pidx; \
    xr##R = x[pidx]; \
    Qcur = Qn_; sW = LIN; \
    ib += 64; }

    for (int kb = 0; kb < 47; ++kb) {   // 47*16 = 752 unclamped iters
        BODY(0,1,  ldsA, ldsB, 0) BODY(1,2,  ldsB, ldsA, 0) BODY(2,3,  ldsA, ldsB, 0) BODY(3,4,  ldsB, ldsA, 0)
        BODY(4,5,  ldsA, ldsB, 0) BODY(5,6,  ldsB, ldsA, 0) BODY(6,7,  ldsA, ldsB, 0) BODY(7,8,  ldsB, ldsA, 0)
        BODY(8,9,  ldsA, ldsB, 0) BODY(9,10, ldsB, ldsA, 0) BODY(10,11,ldsA, ldsB, 0) BODY(11,12,ldsB, ldsA, 0)
        BODY(12,13,ldsA, ldsB, 0) BODY(13,14,ldsB, ldsA, 0) BODY(14,15,ldsA, ldsB, 0) BODY(15,0, ldsB, ldsA, 0)
    }
    // 13 unclamped: k = 752..764
    BODY(0,1,  ldsA, ldsB, 0) BODY(1,2,  ldsB, ldsA, 0) BODY(2,3,  ldsA, ldsB, 0) BODY(3,4,  ldsB, ldsA, 0)
    BODY(4,5,  ldsA, ldsB, 0) BODY(5,6,  ldsB, ldsA, 0) BODY(6,7,  ldsA, ldsB, 0) BODY(7,8,  ldsB, ldsA, 0)
    BODY(8,9,  ldsA, ldsB, 0) BODY(9,10, ldsB, ldsA, 0) BODY(10,11,ldsA, ldsB, 0) BODY(11,12,ldsB, ldsA, 0)
    BODY(12,13,ldsA, ldsB, 0)
    // 15 clamped: k = 765..779
    BODY(13,14,ldsB, ldsA, 1) BODY(14,15,ldsA, ldsB, 1) BODY(15,0, ldsB, ldsA, 1)
    BODY(0,1,  ldsA, ldsB, 1) BODY(1,2,  ldsB, ldsA, 1) BODY(2,3,  ldsA, ldsB, 1) BODY(3,4,  ldsB, ldsA, 1)
    BODY(4,5,  ldsA, ldsB, 1) BODY(5,6,  ldsB, ldsA, 1) BODY(6,7,  ldsA, ldsB, 1) BODY(7,8,  ldsB, ldsA, 1)
    BODY(8,9,  ldsA, ldsB, 1) BODY(9,10, ldsB, ldsA, 1) BODY(10,11,ldsA, ldsB, 1) BODY(11,12,ldsB, ldsA, 1)
#undef BODY

    {   // chunk 780
        float lvl = fmaf(pl, lpv, Qcur);
        lpv = readlane_f(lvl, 63);
        float w_ = fmaf(omg, sW, (g * xr12) * __builtin_amdgcn_rcpf(lvl));
        float2 pk_; pk_.x = lvl; pk_.y = w_;
        *(float2*)&lw[2 * (49921 + lane)] = pk_;
    }
    {   // chunk 781 (lanes 0..14)
        float Qn_; SCAN(Qn_, xr13, __builtin_amdgcn_rcpf(ldsA));
        float lvl = fmaf(pl, lpv, Qn_);
        if (lane < 15) {
            float w_ = fmaf(omg, ldsA, (g * xr13) * __builtin_amdgcn_rcpf(lvl));
            float2 pk_; pk_.x = lvl; pk_.y = w_;
            *(float2*)&lw[2 * (49985 + lane)] = pk_;
        }
    }
#undef SCAN
}

// ---------------- logs + loss partials: F, llev from packed lw ------------------------------
__global__ void k_logs(const float* __restrict__ x, const float* __restrict__ lw,
                       const float* __restrict__ seasinit,
                       float* __restrict__ F, float* __restrict__ llev,
                       float* __restrict__ partials) {
    __shared__ float sm[258];
    __shared__ float red[256];
    int tid = threadIdx.x;
    int t = blockIdx.x * 256 + tid;
    float ll = 0.f;
    if (t < T_LEN) {
        float2 cur = *(const float2*)&lw[2 * t];
        int ps = t - S_LEN; if (ps < 0) ps = 0;
        float sv = (t <= S_LEN) ? seasinit[t] : lw[2 * ps + 1];
        F[t]  = __logf(x[t]) - __logf(sv);
        ll    = __logf(cur.x);
        llev[t] = ll;
    }
    sm[tid] = ll;
    if (tid < 2) {
        int te = blockIdx.x * 256 + 256 + tid;
        sm[256 + tid] = (te < T_LEN) ? __logf(lw[2 * te]) : 0.f;
    }
    __syncthreads();
    float s = 0.f;
    if (t < T_LEN - 2) {
        float d = sm[tid + 2] - 2.f * sm[tid + 1] + sm[tid];
        s = d * d;
    }
    red[tid] = s; __syncthreads();
    for (int off = 128; off > 0; off >>= 1) {
        if (tid < off) red[tid] += red[tid + off];
        __syncthreads();
    }
    if (tid == 0) partials[blockIdx.x] = red[0];
}

// ------- fused GEMM: 8 waves/block, 16-row wave tile (44 AGPR) -> 16 waves/CU ---------------
__global__ __launch_bounds__(512, 2) void k_gemm(
        const float* __restrict__ noise, const float* __restrict__ F,
        const float* __restrict__ llev, const short* __restrict__ W1T,
        const float* __restrict__ b1, const short* __restrict__ W2T,
        const float* __restrict__ b2, const float* __restrict__ S1,
        const float* __restrict__ partials, const int* __restrict__ lvp,
        float* __restrict__ out, float* __restrict__ labels, float* __restrict__ loss) {
    __shared__ __align__(16) short hlds[64][360];   // 46080 B (cols 336..351 exact zeros)
    __shared__ __align__(16) float Flds[448];
    __shared__ __align__(16) float Llds[64];
    __shared__ __align__(16) float b1lds[352];
    __shared__ __align__(16) float S1lds[352];      // total 50944 B

    int t = threadIdx.x, w = t >> 6, l = t & 63;
    int lm = l & 15, lq = l >> 4;
    long n0 = (long)blockIdx.x * 64;

    // loss final (block 0, wave 7)
    if (blockIdx.x == 0 && w == 7) {
        float s = partials[l] + partials[l + 64] + partials[l + 128];
        if (l < 4) s += partials[l + 192];
#pragma unroll
        for (int off = 32; off > 0; off >>= 1) s += __shfl_down(s, off, 64);
        if (l == 0) loss[0] = s / (float)(T_LEN - 2) * (float)lvp[0];
    }

    // stage Flds / Llds / b1lds / S1lds (512 threads -> one shot)
    if (t < 112)      *(f32x4*)&Flds[t * 4] = *(const f32x4*)&F[n0 + t * 4];
    else if (t < 128) *(f32x4*)&Llds[(t - 112) * 4] = *(const f32x4*)&llev[n0 + W_IN + (t - 112) * 4];
    else if (t < 216) {
        int i4 = (t - 128) * 4;
        f32x4 v = (f32x4){0.f, 0.f, 0.f, 0.f};
        if (i4 < W_IN) v = *(const f32x4*)&b1[i4];
        *(f32x4*)&b1lds[i4] = v;
    } else if (t < 304) {
        int i4 = (t - 216) * 4;
        *(f32x4*)&S1lds[i4] = *(const f32x4*)&S1[i4];
    }

    int rbase = (w >> 1) * 16;     // 0,16,32,48  (wave pairs share a row group)
    int jbase = (w & 1) * 176;     // j half
    long an0 = n0 + rbase + lm; if (an0 > N_ROWS - 2) an0 = N_ROWS - 2;
    const float* nr0 = noise + an0 * W_IN + lq * 8;

    // noise prefetch 2-deep (E = even ks, O = odd ks)
    f32x4 ncE0 = *(const f32x4*)&nr0[0],  ncE1 = *(const f32x4*)&nr0[4];
    f32x4 ncO0 = *(const f32x4*)&nr0[32], ncO1 = *(const f32x4*)&nr0[36];

    f32x4 acc[11];
#pragma unroll
    for (int c = 0; c < 11; ++c) acc[c] = (f32x4){0.f, 0.f, 0.f, 0.f};

    __syncthreads();

    const short* w1row = &W1T[(jbase + lm) * 352 + lq * 8];
#define LDW(CT, KS) (*(const s16x8*)&w1row[(CT) * 5632 + (KS) * 32])
#define MM(CT, AF) acc[CT] = __builtin_amdgcn_mfma_f32_16x16x32_bf16(AF, bf0, acc[CT], 0, 0, 0);

#define KSTEP(KS, NC0, NC1) { \
    s16x8 bf0; \
    { int fb = rbase + lm + (KS) * 32 + lq * 8; \
      int* b0i = (int*)&bf0; \
      b0i[0] = bfpk(Flds[fb+0] + NC0[0], Flds[fb+1] + NC0[1]); \
      b0i[1] = bfpk(Flds[fb+2] + NC0[2], Flds[fb+3] + NC0[3]); \
      b0i[2] = bfpk(Flds[fb+4] + NC1[0], Flds[fb+5] + NC1[1]); \
      b0i[3] = bfpk(Flds[fb+6] + NC1[2], Flds[fb+7] + NC1[3]); } \
    if ((KS) + 2 <= 10) { \
      NC0 = *(const f32x4*)&nr0[((KS)+2)*32]; \
      NC1 = *(const f32x4*)&nr0[((KS)+2)*32+4]; \
    } \
    s16x8 af0 = LDW(0,KS), af1 = LDW(1,KS), af2 = LDW(2,KS); \
    MM(0, af0)  af0 = LDW(3,KS); \
    MM(1, af1)  af1 = LDW(4,KS); \
    MM(2, af2)  af2 = LDW(5,KS); \
    MM(3, af0)  af0 = LDW(6,KS); \
    MM(4, af1)  af1 = LDW(7,KS); \
    MM(5, af2)  af2 = LDW(8,KS); \
    MM(6, af0)  af0 = LDW(9,KS); \
    MM(7, af1)  af1 = LDW(10,KS); \
    MM(8, af2) \
    MM(9, af0) \
    MM(10, af1) \
}

    KSTEP(0, ncE0, ncE1) KSTEP(1, ncO0, ncO1) KSTEP(2, ncE0, ncE1) KSTEP(3, ncO0, ncO1)
    KSTEP(4, ncE0, ncE1) KSTEP(5, ncO0, ncO1) KSTEP(6, ncE0, ncE1) KSTEP(7, ncO0, ncO1)
    KSTEP(8, ncE0, ncE1) KSTEP(9, ncO0, ncO1) KSTEP(10, ncE0, ncE1)
#undef KSTEP
#undef MM
#undef LDW

    // epilogue 1: h = tanh(acc + b1 - lv*S1) -> hlds
    float lv0 = Llds[rbase + lm];
#pragma unroll
    for (int ct = 0; ct < 11; ++ct) {
        f32x4 b1q = *(f32x4*)&b1lds[jbase + ct * 16 + lq * 4];
        f32x4 s1q = *(f32x4*)&S1lds[jbase + ct * 16 + lq * 4];
        int2 p0;
        p0.x = bfpk(fast_tanh(fmaf(-lv0, s1q[0], acc[ct][0] + b1q[0])),
                    fast_tanh(fmaf(-lv0, s1q[1], acc[ct][1] + b1q[1])));
        p0.y = bfpk(fast_tanh(fmaf(-lv0, s1q[2], acc[ct][2] + b1q[2])),
                    fast_tanh(fmaf(-lv0, s1q[3], acc[ct][3] + b1q[3])));
        *(int2*)&hlds[rbase + lm][jbase + ct * 16 + lq * 4] = p0;
    }
    __syncthreads();

    if (w < 4) {
        // gemm2: rows w*16..w*16+15; out stores
        f32x4 a2[3];
        a2[0] = (f32x4){0,0,0,0}; a2[1] = (f32x4){0,0,0,0}; a2[2] = (f32x4){0,0,0,0};
#pragma unroll
        for (int ks = 0; ks < 11; ++ks) {
            s16x8 hf = *(s16x8*)&hlds[w * 16 + lm][ks * 32 + lq * 8];
#pragma unroll
            for (int ct = 0; ct < 3; ++ct) {
                s16x8 bf2 = *(const s16x8*)&W2T[(ct * 16 + lm) * 360 + ks * 32 + lq * 8];
                a2[ct] = __builtin_amdgcn_mfma_f32_16x16x32_bf16(hf, bf2, a2[ct], 0, 0, 0);
            }
        }
        int rloc = w * 16 + lq * 4;
#pragma unroll
        for (int ct = 0; ct < 3; ++ct) {
            float b2v = b2[ct * 16 + lm];
#pragma unroll
            for (int r = 0; r < 4; ++r) {
                long row = n0 + rloc + r;
                if (row < N_ROWS) out[row * O_OUT + ct * 16 + lm] = a2[ct][r] + b2v;
            }
        }
    } else {
        // labels: rows (w-4)*16 .. +15; 4 lanes per row, 12 cols each
        int rb2 = (w - 4) * 16;
        int lrow = l >> 2, cbase = (l & 3) * 12;
        long row = n0 + rb2 + lrow;
        if (row < N_ROWS) {
            float fl = -Llds[rb2 + lrow];
            const float* fp = &Flds[rb2 + lrow + W_IN + cbase];
            float* lp = &labels[row * O_OUT + cbase];
#pragma unroll
            for (int i = 0; i < 12; ++i) lp[i] = fp[i] + fl;
        }
    }
}

extern "C" void kernel_launch(void* const* d_in, const int* in_sizes, int n_in,
                              void* d_out, int out_size, void* d_ws, size_t ws_size,
                              hipStream_t stream) {
    const float* x         = (const float*)d_in[0];
    const float* noise     = (const float*)d_in[1];
    const float* level_sc  = (const float*)d_in[2];
    const float* seas_sc   = (const float*)d_in[3];
    const float* init_seas = (const float*)d_in[4];
    const float* W1        = (const float*)d_in[5];
    const float* b1        = (const float*)d_in[6];
    const float* W2        = (const float*)d_in[7];
    const float* b2        = (const float*)d_in[8];
    const int*   lvp       = (const int*)d_in[11];

    float* out    = (float*)d_out;
    float* labels = out + (long)N_ROWS * O_OUT;
    float* loss   = labels + (long)N_ROWS * O_OUT;

    float* wsf      = (float*)d_ws;
    float* lw       = wsf;                 // 2*50000 packed {level,w} (reserve 100096)
    float* seasinit = wsf + 100096;        // 169 (reserve 192)
    float* F        = wsf + 100288;        // 50000 (reserve 50176)
    float* llev     = wsf + 150464;        // 50000 (reserve 50048)
    float* partials = wsf + 200512;        // 196 (reserve 256)
    float* S1f      = wsf + 200768;        // 352 (reserve 384)
    short* W1T      = (short*)(wsf + 201152);   // 352*352 bf16 (zero-padded)
    short* W2T      = W1T + 352 * 352;          // 48*360 bf16

    k_preconvert<<<554, 256, 0, stream>>>(W1, W2, W1T, W2T, S1f);
    k_scan<<<1, 64, 0, stream>>>(x, level_sc, seas_sc, init_seas, lw, seasinit);
    k_logs<<<196, 256, 0, stream>>>(x, lw, seasinit, F, llev, partials);
    k_gemm<<<NBLK, 512, 0, stream>>>(noise, F, llev, W1T, b1, W2T, b2, S1f,
                                     partials, lvp, out, labels, loss);
}

// Round 12
// 175.008 us; speedup vs baseline: 1.0019x; 1.0019x over previous
//
#include <hip/hip_runtime.h>
#include <hip/hip_bf16.h>

typedef __attribute__((ext_vector_type(8))) short  s16x8;   // 8 x bf16
typedef __attribute__((ext_vector_type(4))) short  s16x4;
typedef __attribute__((ext_vector_type(4))) float  f32x4;

#define T_LEN 50000
#define S_LEN 168
#define W_IN  336
#define O_OUT 48
#define N_ROWS (T_LEN - W_IN - O_OUT + 1)   // 49617
#define N_PAD  49664                        // 776 * 64
#define NBLK   (N_PAD / 64)                 // 776

__device__ inline short f2bf(float f) {
    union { float f; unsigned u; } v; v.f = f;
    unsigned u = v.u;
    unsigned r = u + 0x7fffu + ((u >> 16) & 1u);   // RNE
    return (short)(r >> 16);
}

__device__ inline int bfpk(float lo, float hi) {   // 2xf32 -> packed 2xbf16 (RNE)
    float2 f2; f2.x = lo; f2.y = hi;
    __hip_bfloat162 h = __float22bfloat162_rn(f2);
    int r; __builtin_memcpy(&r, &h, 4);
    return r;
}

__device__ inline float readlane_f(float v, int l) {
    return __int_as_float(__builtin_amdgcn_readlane(__float_as_int(v), l));
}

__device__ inline float fast_tanh(float v) {
    float e = __expf(2.f * v);
    return 1.f - 2.f * __builtin_amdgcn_rcpf(e + 1.f);
}

// ---- pre-convert W1 -> W1T bf16 [352][352], W2 -> W2T [48][360], S1[j] = colsum(W1) -------
__global__ void k_preconvert(const float* __restrict__ W1, const float* __restrict__ W2,
                             short* __restrict__ W1T, short* __restrict__ W2T,
                             float* __restrict__ S1) {
    int idx = blockIdx.x * 256 + threadIdx.x;
    const int n1 = 352 * 352;
    const int n2 = n1 + 48 * 360;
    if (idx < n1) {
        int j = idx / 352, k = idx % 352;
        W1T[idx] = (j < 336 && k < 336) ? f2bf(W1[k * 336 + j]) : (short)0;
    } else if (idx < n2) {
        int i2 = idx - n1;
        int o = i2 / 360, k = i2 % 360;
        W2T[i2] = (k < 336) ? f2bf(W2[k * 48 + o]) : (short)0;
    } else if (idx < n2 + 352) {
        int j = idx - n2;
        float s = 0.f;
        if (j < 336)
            for (int k = 0; k < 336; ++k) s += W1[k * 336 + j];
        S1[j] = s;
    }
}

// ---------------- scan: packed lw stores, row_bcast DPP scan, peeled clamp -----------------
#define DPP_FMA(q_, CTRL, W, RM) { \
    int t_ = __builtin_amdgcn_update_dpp(0, __float_as_int(q_), (CTRL), (RM), 0xf, true); \
    q_ = fmaf((W), __int_as_float(t_), q_); }

__global__ void k_scan(const float* __restrict__ x, const float* __restrict__ level_sc,
                       const float* __restrict__ seas_sc, const float* __restrict__ init_seas,
                       float* __restrict__ lw, float* __restrict__ seasinit) {
    __shared__ float ring[256];      // ring[s & 255] = seas(s)
    int lane = threadIdx.x;          // 64 threads, 1 wave
    float a = 1.f / (1.f + expf(-level_sc[0]));
    float g = 1.f / (1.f + expf(-seas_sc[0]));
    float om = 1.f - a, omg = 1.f - g;

    for (int t = lane; t < 256; t += 64) {
        float s = 1.f;
        if (t <= S_LEN) { s = expf(init_seas[t < S_LEN ? t : 0]); seasinit[t] = s; }
        ring[t] = s;
    }
    float lpv = x[0] / expf(init_seas[0]);
    if (lane == 0) { lw[0] = lpv; lw[1] = 1.f; }
    __syncthreads();

    float om1 = om, om2v = om1 * om1, om4 = om2v * om2v, om8 = om4 * om4;
    float pl    = powf(om, (float)(lane + 1));
    float fpre  = powf(om, (float)((lane & 15) + 1));
    float fpre2 = powf(om, (float)((lane & 31) + 1));

#define SCAN(QOUT, XV, RSV) { \
    float q_ = a * (XV) * (RSV); \
    DPP_FMA(q_, 0x111, om1,  0xf); \
    DPP_FMA(q_, 0x112, om2v, 0xf); \
    DPP_FMA(q_, 0x114, om4,  0xf); \
    DPP_FMA(q_, 0x118, om8,  0xf); \
    DPP_FMA(q_, 0x142, fpre,  0xa); \
    DPP_FMA(q_, 0x143, fpre2, 0xc); \
    QOUT = q_; }

#define XLOAD(I) float xr##I = x[1 + 64 * I + lane];
    XLOAD(0) XLOAD(1) XLOAD(2) XLOAD(3) XLOAD(4) XLOAD(5) XLOAD(6) XLOAD(7)
    XLOAD(8) XLOAD(9) XLOAD(10) XLOAD(11) XLOAD(12) XLOAD(13) XLOAD(14) XLOAD(15)
#undef XLOAD

    float sA0 = ring[1 + lane];
    float Qcur; SCAN(Qcur, xr0, __builtin_amdgcn_rcpf(sA0));
    float sW = sA0;
    float ldsA = ring[65 + lane];
    float ldsB;
    int ib = 1;

#define BODY(R, RN, LIN, LOUT, CLAMP) { \
    float lvl = fmaf(pl, lpv, Qcur); \
    lpv = readlane_f(lvl, 63); \
    float w_ = fmaf(omg, sW, (g * xr##R) * __builtin_amdgcn_rcpf(lvl)); \
    float2 pk_; pk_.x = lvl; pk_.y = w_; \
    *(float2*)&lw[2 * (ib + lane)] = pk_; \
    ring[(ib + S_LEN + lane) & 255] = w_; \
    LOUT = ring[(ib + 128 + lane) & 255]; \
    float Qn_; SCAN(Qn_, xr##RN, __builtin_amdgcn_rcpf(LIN)); \
    int pidx = ib + 1024 + lane; \
    if (CLAMP) pidx = pidx > (T_LEN - 1) ? (T_LEN - 1) : pidx; \
    xr##R = x[pidx]; \
    Qcur = Qn_; sW = LIN; \
    ib += 64; }

    for (int kb = 0; kb < 47; ++kb) {   // 47*16 = 752 unclamped iters
        BODY(0,1,  ldsA, ldsB, 0) BODY(1,2,  ldsB, ldsA, 0) BODY(2,3,  ldsA, ldsB, 0) BODY(3,4,  ldsB, ldsA, 0)
        BODY(4,5,  ldsA, ldsB, 0) BODY(5,6,  ldsB, ldsA, 0) BODY(6,7,  ldsA, ldsB, 0) BODY(7,8,  ldsB, ldsA, 0)
        BODY(8,9,  ldsA, ldsB, 0) BODY(9,10, ldsB, ldsA, 0) BODY(10,11,ldsA, ldsB, 0) BODY(11,12,ldsB, ldsA, 0)
        BODY(12,13,ldsA, ldsB, 0) BODY(13,14,ldsB, ldsA, 0) BODY(14,15,ldsA, ldsB, 0) BODY(15,0, ldsB, ldsA, 0)
    }
    // 13 unclamped: k = 752..764
    BODY(0,1,  ldsA, ldsB, 0) BODY(1,2,  ldsB, ldsA, 0) BODY(2,3,  ldsA, ldsB, 0) BODY(3,4,  ldsB, ldsA, 0)
    BODY(4,5,  ldsA, ldsB, 0) BODY(5,6,  ldsB, ldsA, 0) BODY(6,7,  ldsA, ldsB, 0) BODY(7,8,  ldsB, ldsA, 0)
    BODY(8,9,  ldsA, ldsB, 0) BODY(9,10, ldsB, ldsA, 0) BODY(10,11,ldsA, ldsB, 0) BODY(11,12,ldsB, ldsA, 0)
    BODY(12,13,ldsA, ldsB, 0)
    // 15 clamped: k = 765..779
    BODY(13,14,ldsB, ldsA, 1) BODY(14,15,ldsA, ldsB, 1) BODY(15,0, ldsB, ldsA, 1)
    BODY(0,1,  ldsA, ldsB, 1) BODY(1,2,  ldsB, ldsA, 1) BODY(2,3,  ldsA, ldsB, 1) BODY(3,4,  ldsB, ldsA, 1)
    BODY(4,5,  ldsA, ldsB, 1) BODY(5,6,  ldsB, ldsA, 1) BODY(6,7,  ldsA, ldsB, 1) BODY(7,8,  ldsB, ldsA, 1)
    BODY(8,9,  ldsA, ldsB, 1) BODY(9,10, ldsB, ldsA, 1) BODY(10,11,ldsA, ldsB, 1) BODY(11,12,ldsB, ldsA, 1)
#undef BODY

    {   // chunk 780
        float lvl = fmaf(pl, lpv, Qcur);
        lpv = readlane_f(lvl, 63);
        float w_ = fmaf(omg, sW, (g * xr12) * __builtin_amdgcn_rcpf(lvl));
        float2 pk_; pk_.x = lvl; pk_.y = w_;
        *(float2*)&lw[2 * (49921 + lane)] = pk_;
    }
    {   // chunk 781 (lanes 0..14)
        float Qn_; SCAN(Qn_, xr13, __builtin_amdgcn_rcpf(ldsA));
        float lvl = fmaf(pl, lpv, Qn_);
        if (lane < 15) {
            float w_ = fmaf(omg, ldsA, (g * xr13) * __builtin_amdgcn_rcpf(lvl));
            float2 pk_; pk_.x = lvl; pk_.y = w_;
            *(float2*)&lw[2 * (49985 + lane)] = pk_;
        }
    }
#undef SCAN
}

// ---------------- logs + loss partials: F, llev from packed lw ------------------------------
__global__ void k_logs(const float* __restrict__ x, const float* __restrict__ lw,
                       const float* __restrict__ seasinit,
                       float* __restrict__ F, float* __restrict__ llev,
                       float* __restrict__ partials) {
    __shared__ float sm[258];
    __shared__ float red[256];
    int tid = threadIdx.x;
    int t = blockIdx.x * 256 + tid;
    float ll = 0.f;
    if (t < T_LEN) {
        float2 cur = *(const float2*)&lw[2 * t];
        int ps = t - S_LEN; if (ps < 0) ps = 0;
        float sv = (t <= S_LEN) ? seasinit[t] : lw[2 * ps + 1];
        F[t]  = __logf(x[t]) - __logf(sv);
        ll    = __logf(cur.x);
        llev[t] = ll;
    }
    sm[tid] = ll;
    if (tid < 2) {
        int te = blockIdx.x * 256 + 256 + tid;
        sm[256 + tid] = (te < T_LEN) ? __logf(lw[2 * te]) : 0.f;
    }
    __syncthreads();
    float s = 0.f;
    if (t < T_LEN - 2) {
        float d = sm[tid + 2] - 2.f * sm[tid + 1] + sm[tid];
        s = d * d;
    }
    red[tid] = s; __syncthreads();
    for (int off = 128; off > 0; off >>= 1) {
        if (tid < off) red[tid] += red[tid + off];
        __syncthreads();
    }
    if (tid == 0) partials[blockIdx.x] = red[0];
}

// ------- fused GEMM: 8 waves/block, 16-row wave tile (44 AGPR) -> 16 waves/CU ---------------
__global__ __launch_bounds__(512, 2) void k_gemm(
        const float* __restrict__ noise, const float* __restrict__ F,
        const float* __restrict__ llev, const short* __restrict__ W1T,
        const float* __restrict__ b1, const short* __restrict__ W2T,
        const float* __restrict__ b2, const float* __restrict__ S1,
        const float* __restrict__ partials, const int* __restrict__ lvp,
        float* __restrict__ out, float* __restrict__ labels, float* __restrict__ loss) {
    __shared__ __align__(16) short hlds[64][360];   // 46080 B (cols 336..351 exact zeros)
    __shared__ __align__(16) float Flds[448];
    __shared__ __align__(16) float Llds[64];
    __shared__ __align__(16) float b1lds[352];
    __shared__ __align__(16) float S1lds[352];      // total 50944 B

    int t = threadIdx.x, w = t >> 6, l = t & 63;
    int lm = l & 15, lq = l >> 4;
    long n0 = (long)blockIdx.x * 64;

    // loss final (block 0, wave 7)
    if (blockIdx.x == 0 && w == 7) {
        float s = partials[l] + partials[l + 64] + partials[l + 128];
        if (l < 4) s += partials[l + 192];
#pragma unroll
        for (int off = 32; off > 0; off >>= 1) s += __shfl_down(s, off, 64);
        if (l == 0) loss[0] = s / (float)(T_LEN - 2) * (float)lvp[0];
    }

    // stage Flds / Llds / b1lds / S1lds (512 threads -> one shot)
    if (t < 112)      *(f32x4*)&Flds[t * 4] = *(const f32x4*)&F[n0 + t * 4];
    else if (t < 128) *(f32x4*)&Llds[(t - 112) * 4] = *(const f32x4*)&llev[n0 + W_IN + (t - 112) * 4];
    else if (t < 216) {
        int i4 = (t - 128) * 4;
        f32x4 v = (f32x4){0.f, 0.f, 0.f, 0.f};
        if (i4 < W_IN) v = *(const f32x4*)&b1[i4];
        *(f32x4*)&b1lds[i4] = v;
    } else if (t < 304) {
        int i4 = (t - 216) * 4;
        *(f32x4*)&S1lds[i4] = *(const f32x4*)&S1[i4];
    }

    int rbase = (w >> 1) * 16;     // 0,16,32,48  (wave pairs share a row group)
    int jbase = (w & 1) * 176;     // j half
    long an0 = n0 + rbase + lm; if (an0 > N_ROWS - 2) an0 = N_ROWS - 2;
    const float* nr0 = noise + an0 * W_IN + lq * 8;

    // noise prefetch 2-deep (E = even ks, O = odd ks)
    f32x4 ncE0 = *(const f32x4*)&nr0[0],  ncE1 = *(const f32x4*)&nr0[4];
    f32x4 ncO0 = *(const f32x4*)&nr0[32], ncO1 = *(const f32x4*)&nr0[36];

    f32x4 acc[11];
#pragma unroll
    for (int c = 0; c < 11; ++c) acc[c] = (f32x4){0.f, 0.f, 0.f, 0.f};

    __syncthreads();

    const short* w1row = &W1T[(jbase + lm) * 352 + lq * 8];
#define LDW(CT, KS) (*(const s16x8*)&w1row[(CT) * 5632 + (KS) * 32])
#define MM(CT, AF) acc[CT] = __builtin_amdgcn_mfma_f32_16x16x32_bf16(AF, bf0, acc[CT], 0, 0, 0);

#define KSTEP(KS, NC0, NC1) { \
    s16x8 bf0; \
    { int fb = rbase + lm + (KS) * 32 + lq * 8; \
      int* b0i = (int*)&bf0; \
      b0i[0] = bfpk(Flds[fb+0] + NC0[0], Flds[fb+1] + NC0[1]); \
      b0i[1] = bfpk(Flds[fb+2] + NC0[2], Flds[fb+3] + NC0[3]); \
      b0i[2] = bfpk(Flds[fb+4] + NC1[0], Flds[fb+5] + NC1[1]); \
      b0i[3] = bfpk(Flds[fb+6] + NC1[2], Flds[fb+7] + NC1[3]); } \
    if ((KS) + 2 <= 10) { \
      NC0 = *(const f32x4*)&nr0[((KS)+2)*32]; \
      NC1 = *(const f32x4*)&nr0[((KS)+2)*32+4]; \
    } \
    s16x8 af0 = LDW(0,KS), af1 = LDW(1,KS), af2 = LDW(2,KS); \
    MM(0, af0)  af0 = LDW(3,KS); \
    MM(1, af1)  af1 = LDW(4,KS); \
    MM(2, af2)  af2 = LDW(5,KS); \
    MM(3, af0)  af0 = LDW(6,KS); \
    MM(4, af1)  af1 = LDW(7,KS); \
    MM(5, af2)  af2 = LDW(8,KS); \
    MM(6, af0)  af0 = LDW(9,KS); \
    MM(7, af1)  af1 = LDW(10,KS); \
    MM(8, af2) \
    MM(9, af0) \
    MM(10, af1) \
}

    KSTEP(0, ncE0, ncE1) KSTEP(1, ncO0, ncO1) KSTEP(2, ncE0, ncE1) KSTEP(3, ncO0, ncO1)
    KSTEP(4, ncE0, ncE1) KSTEP(5, ncO0, ncO1) KSTEP(6, ncE0, ncE1) KSTEP(7, ncO0, ncO1)
    KSTEP(8, ncE0, ncE1) KSTEP(9, ncO0, ncO1) KSTEP(10, ncE0, ncE1)
#undef KSTEP
#undef MM
#undef LDW

    // epilogue 1: h = tanh(acc + b1 - lv*S1) -> hlds
    float lv0 = Llds[rbase + lm];
#pragma unroll
    for (int ct = 0; ct < 11; ++ct) {
        f32x4 b1q = *(f32x4*)&b1lds[jbase + ct * 16 + lq * 4];
        f32x4 s1q = *(f32x4*)&S1lds[jbase + ct * 16 + lq * 4];
        int2 p0;
        p0.x = bfpk(fast_tanh(fmaf(-lv0, s1q[0], acc[ct][0] + b1q[0])),
                    fast_tanh(fmaf(-lv0, s1q[1], acc[ct][1] + b1q[1])));
        p0.y = bfpk(fast_tanh(fmaf(-lv0, s1q[2], acc[ct][2] + b1q[2])),
                    fast_tanh(fmaf(-lv0, s1q[3], acc[ct][3] + b1q[3])));
        *(int2*)&hlds[rbase + lm][jbase + ct * 16 + lq * 4] = p0;
    }
    __syncthreads();

    if (w < 4) {
        // gemm2: rows w*16..w*16+15; out stores
        f32x4 a2[3];
        a2[0] = (f32x4){0,0,0,0}; a2[1] = (f32x4){0,0,0,0}; a2[2] = (f32x4){0,0,0,0};
#pragma unroll
        for (int ks = 0; ks < 11; ++ks) {
            s16x8 hf = *(s16x8*)&hlds[w * 16 + lm][ks * 32 + lq * 8];
#pragma unroll
            for (int ct = 0; ct < 3; ++ct) {
                s16x8 bf2 = *(const s16x8*)&W2T[(ct * 16 + lm) * 360 + ks * 32 + lq * 8];
                a2[ct] = __builtin_amdgcn_mfma_f32_16x16x32_bf16(hf, bf2, a2[ct], 0, 0, 0);
            }
        }
        int rloc = w * 16 + lq * 4;
#pragma unroll
        for (int ct = 0; ct < 3; ++ct) {
            float b2v = b2[ct * 16 + lm];
#pragma unroll
            for (int r = 0; r < 4; ++r) {
                long row = n0 + rloc + r;
                if (row < N_ROWS) out[row * O_OUT + ct * 16 + lm] = a2[ct][r] + b2v;
            }
        }
    } else {
        // labels: rows (w-4)*16 .. +15; 4 lanes per row, 12 cols each
        int rb2 = (w - 4) * 16;
        int lrow = l >> 2, cbase = (l & 3) * 12;
        long row = n0 + rb2 + lrow;
        if (row < N_ROWS) {
            float fl = -Llds[rb2 + lrow];
            const float* fp = &Flds[rb2 + lrow + W_IN + cbase];
            float* lp = &labels[row * O_OUT + cbase];
#pragma unroll
            for (int i = 0; i < 12; ++i) lp[i] = fp[i] + fl;
        }
    }
}

extern "C" void kernel_launch(void* const* d_in, const int* in_sizes, int n_in,
                              void* d_out, int out_size, void* d_ws, size_t ws_size,
                              hipStream_t stream) {
    const float* x         = (const float*)d_in[0];
    const float* noise     = (const float*)d_in[1];
    const float* level_sc  = (const float*)d_in[2];
    const float* seas_sc   = (const float*)d_in[3];
    const float* init_seas = (const float*)d_in[4];
    const float* W1        = (const float*)d_in[5];
    const float* b1        = (const float*)d_in[6];
    const float* W2        = (const float*)d_in[7];
    const float* b2        = (const float*)d_in[8];
    const int*   lvp       = (const int*)d_in[11];

    float* out    = (float*)d_out;
    float* labels = out + (long)N_ROWS * O_OUT;
    float* loss   = labels + (long)N_ROWS * O_OUT;

    float* wsf      = (float*)d_ws;
    float* lw       = wsf;                 // 2*50000 packed {level,w} (reserve 100096)
    float* seasinit = wsf + 100096;        // 169 (reserve 192)
    float* F        = wsf + 100288;        // 50000 (reserve 50176)
    float* llev     = wsf + 150464;        // 50000 (reserve 50048)
    float* partials = wsf + 200512;        // 196 (reserve 256)
    float* S1f      = wsf + 200768;        // 352 (reserve 384)
    short* W1T      = (short*)(wsf + 201152);   // 352*352 bf16 (zero-padded)
    short* W2T      = W1T + 352 * 352;          // 48*360 bf16

    k_preconvert<<<554, 256, 0, stream>>>(W1, W2, W1T, W2T, S1f);
    k_scan<<<1, 64, 0, stream>>>(x, level_sc, seas_sc, init_seas, lw, seasinit);
    k_logs<<<196, 256, 0, stream>>>(x, lw, seasinit, F, llev, partials);
    k_gemm<<<NBLK, 512, 0, stream>>>(noise, F, llev, W1T, b1, W2T, b2, S1f,
                                     partials, lvp, out, labels, loss);
}

// Round 13
// 162.045 us; speedup vs baseline: 1.0820x; 1.0800x over previous
//
#include <hip/hip_runtime.h>
#include <hip/hip_bf16.h>

typedef __attribute__((ext_vector_type(8))) short  s16x8;   // 8 x bf16
typedef __attribute__((ext_vector_type(4))) short  s16x4;
typedef __attribute__((ext_vector_type(4))) float  f32x4;

#define T_LEN 50000
#define S_LEN 168
#define W_IN  336
#define O_OUT 48
#define N_ROWS (T_LEN - W_IN - O_OUT + 1)   // 49617
#define N_PAD  49664                        // 776 * 64
#define NBLK   (N_PAD / 64)                 // 776

__device__ inline short f2bf(float f) {
    union { float f; unsigned u; } v; v.f = f;
    unsigned u = v.u;
    unsigned r = u + 0x7fffu + ((u >> 16) & 1u);   // RNE
    return (short)(r >> 16);
}

__device__ inline int bfpk(float lo, float hi) {   // 2xf32 -> packed 2xbf16 (RNE)
    float2 f2; f2.x = lo; f2.y = hi;
    __hip_bfloat162 h = __float22bfloat162_rn(f2);
    int r; __builtin_memcpy(&r, &h, 4);
    return r;
}

__device__ inline float readlane_f(float v, int l) {
    return __int_as_float(__builtin_amdgcn_readlane(__float_as_int(v), l));
}

__device__ inline float fast_tanh(float v) {
    float e = __expf(2.f * v);
    return 1.f - 2.f * __builtin_amdgcn_rcpf(e + 1.f);
}

// ---- pre-convert W1 -> W1T bf16 [352][352], W2 -> W2T [48][360], S1[j] = colsum(W1) -------
__global__ void k_preconvert(const float* __restrict__ W1, const float* __restrict__ W2,
                             short* __restrict__ W1T, short* __restrict__ W2T,
                             float* __restrict__ S1) {
    int idx = blockIdx.x * 256 + threadIdx.x;
    const int n1 = 352 * 352;
    const int n2 = n1 + 48 * 360;
    if (idx < n1) {
        int j = idx / 352, k = idx % 352;
        W1T[idx] = (j < 336 && k < 336) ? f2bf(W1[k * 336 + j]) : (short)0;
    } else if (idx < n2) {
        int i2 = idx - n1;
        int o = i2 / 360, k = i2 % 360;
        W2T[i2] = (k < 336) ? f2bf(W2[k * 48 + o]) : (short)0;
    } else if (idx < n2 + 352) {
        int j = idx - n2;
        float s = 0.f;
        if (j < 336)
            for (int k = 0; k < 336; ++k) s += W1[k * 336 + j];
        S1[j] = s;
    }
}

// ------- scan: ringless — seas via 2x ds_bpermute from w registers; row_bcast DPP scan -----
#define DPP_FMA(q_, CTRL, W, RM) { \
    int t_ = __builtin_amdgcn_update_dpp(0, __float_as_int(q_), (CTRL), (RM), 0xf, true); \
    q_ = fmaf((W), __int_as_float(t_), q_); }

__global__ void k_scan(const float* __restrict__ x, const float* __restrict__ level_sc,
                       const float* __restrict__ seas_sc, const float* __restrict__ init_seas,
                       float* __restrict__ lw, float* __restrict__ seasinit) {
    int lane = threadIdx.x;          // 64 threads, 1 wave
    float a = 1.f / (1.f + expf(-level_sc[0]));
    float g = 1.f / (1.f + expf(-seas_sc[0]));
    float om = 1.f - a, omg = 1.f - g;

    // seasinit[0..168] for k_logs
    for (int t = lane; t <= S_LEN; t += 64)
        seasinit[t] = expf(init_seas[t < S_LEN ? t : 0]);

    float lpv = x[0] / expf(init_seas[0]);
    if (lane == 0) { lw[0] = lpv; lw[1] = 1.f; }

    float om1 = om, om2v = om1 * om1, om4 = om2v * om2v, om8 = om4 * om4;
    float pl    = powf(om, (float)(lane + 1));
    float fpre  = powf(om, (float)((lane & 15) + 1));
    float fpre2 = powf(om, (float)((lane & 31) + 1));

    // seas(chunk m, lane j) = j<40 ? w(chunk m-3, j+24) : w(chunk m-2, j-40)
    int  idx4 = ((lane + 24) & 63) << 2;   // bpermute byte addr
    bool lowj = (lane < 40);

#define SCAN(QOUT, XV, RSV) { \
    float q_ = a * (XV) * (RSV); \
    DPP_FMA(q_, 0x111, om1,  0xf); \
    DPP_FMA(q_, 0x112, om2v, 0xf); \
    DPP_FMA(q_, 0x114, om4,  0xf); \
    DPP_FMA(q_, 0x118, om8,  0xf); \
    DPP_FMA(q_, 0x142, fpre,  0xa); \
    DPP_FMA(q_, 0x143, fpre2, 0xc); \
    QOUT = q_; }

#define XLOAD(I) float xr##I = x[1 + 64 * I + lane];
    XLOAD(0) XLOAD(1) XLOAD(2) XLOAD(3) XLOAD(4) XLOAD(5) XLOAD(6) XLOAD(7)
    XLOAD(8) XLOAD(9) XLOAD(10) XLOAD(11) XLOAD(12) XLOAD(13) XLOAD(14) XLOAD(15)
#undef XLOAD

    // prologue: seas(0),(1) + virtual wPrev (chunk -1) from init seasonals
    float sW = expf(init_seas[1 + lane]);       // seas(chunk0): p=1+j in [1,64]
    float sN = expf(init_seas[65 + lane]);      // seas(chunk1): p in [65,128]
    int t105 = 105 + lane;                      // lane i holds seas(105+i); i=63 -> 168 -> init[0]
    float wPrev = expf(init_seas[t105 >= S_LEN ? 0 : t105]);
    float Qcur; SCAN(Qcur, xr0, __builtin_amdgcn_rcpf(sW));
    int ib = 1;

    // iter k: propagate chunk k; seas(k+2) via bpermute(wPrev=w(k-1), w_=w(k));
    //         scan chunk k+1 with sN; prefetch x chunk k+16.
#define BODY(R, RN, CLAMP) { \
    float lvl = fmaf(pl, lpv, Qcur); \
    lpv = readlane_f(lvl, 63); \
    float w_ = fmaf(omg, sW, (g * xr##R) * __builtin_amdgcn_rcpf(lvl)); \
    float2 pk_; pk_.x = lvl; pk_.y = w_; \
    *(float2*)&lw[2 * (ib + lane)] = pk_; \
    int tA_ = __builtin_amdgcn_ds_bpermute(idx4, __float_as_int(wPrev)); \
    int tB_ = __builtin_amdgcn_ds_bpermute(idx4, __float_as_int(w_)); \
    float sNN_ = lowj ? __int_as_float(tA_) : __int_as_float(tB_); \
    float Qn_; SCAN(Qn_, xr##RN, __builtin_amdgcn_rcpf(sN)); \
    int pidx = ib + 1024 + lane; \
    if (CLAMP) pidx = pidx > (T_LEN - 1) ? (T_LEN - 1) : pidx; \
    xr##R = x[pidx]; \
    Qcur = Qn_; sW = sN; sN = sNN_; wPrev = w_; \
    ib += 64; }

    for (int kb = 0; kb < 47; ++kb) {   // 47*16 = 752 unclamped iters
        BODY(0,1,0)  BODY(1,2,0)  BODY(2,3,0)  BODY(3,4,0)
        BODY(4,5,0)  BODY(5,6,0)  BODY(6,7,0)  BODY(7,8,0)
        BODY(8,9,0)  BODY(9,10,0) BODY(10,11,0) BODY(11,12,0)
        BODY(12,13,0) BODY(13,14,0) BODY(14,15,0) BODY(15,0,0)
    }
    // 13 unclamped: k = 752..764
    BODY(0,1,0)  BODY(1,2,0)  BODY(2,3,0)  BODY(3,4,0)
    BODY(4,5,0)  BODY(5,6,0)  BODY(6,7,0)  BODY(7,8,0)
    BODY(8,9,0)  BODY(9,10,0) BODY(10,11,0) BODY(11,12,0)
    BODY(12,13,0)
    // 15 clamped: k = 765..779
    BODY(13,14,1) BODY(14,15,1) BODY(15,0,1)
    BODY(0,1,1)  BODY(1,2,1)  BODY(2,3,1)  BODY(3,4,1)
    BODY(4,5,1)  BODY(5,6,1)  BODY(6,7,1)  BODY(7,8,1)
    BODY(8,9,1)  BODY(9,10,1) BODY(10,11,1) BODY(11,12,1)
#undef BODY

    {   // chunk 780 (steps 49921..49984; sW = seas(780), Qcur = Q(780))
        float lvl = fmaf(pl, lpv, Qcur);
        lpv = readlane_f(lvl, 63);
        float w_ = fmaf(omg, sW, (g * xr12) * __builtin_amdgcn_rcpf(lvl));
        float2 pk_; pk_.x = lvl; pk_.y = w_;
        *(float2*)&lw[2 * (49921 + lane)] = pk_;
    }
    {   // chunk 781 (steps 49985..49999, lanes 0..14; sN = seas(781))
        float Qn_; SCAN(Qn_, xr13, __builtin_amdgcn_rcpf(sN));
        float lvl = fmaf(pl, lpv, Qn_);
        if (lane < 15) {
            float w_ = fmaf(omg, sN, (g * xr13) * __builtin_amdgcn_rcpf(lvl));
            float2 pk_; pk_.x = lvl; pk_.y = w_;
            *(float2*)&lw[2 * (49985 + lane)] = pk_;
        }
    }
#undef SCAN
}

// ---------------- logs + loss partials: F, llev from packed lw ------------------------------
__global__ void k_logs(const float* __restrict__ x, const float* __restrict__ lw,
                       const float* __restrict__ seasinit,
                       float* __restrict__ F, float* __restrict__ llev,
                       float* __restrict__ partials) {
    __shared__ float sm[258];
    __shared__ float red[256];
    int tid = threadIdx.x;
    int t = blockIdx.x * 256 + tid;
    float ll = 0.f;
    if (t < T_LEN) {
        float2 cur = *(const float2*)&lw[2 * t];
        int ps = t - S_LEN; if (ps < 0) ps = 0;
        float sv = (t <= S_LEN) ? seasinit[t] : lw[2 * ps + 1];
        F[t]  = __logf(x[t]) - __logf(sv);
        ll    = __logf(cur.x);
        llev[t] = ll;
    }
    sm[tid] = ll;
    if (tid < 2) {
        int te = blockIdx.x * 256 + 256 + tid;
        sm[256 + tid] = (te < T_LEN) ? __logf(lw[2 * te]) : 0.f;
    }
    __syncthreads();
    float s = 0.f;
    if (t < T_LEN - 2) {
        float d = sm[tid + 2] - 2.f * sm[tid + 1] + sm[tid];
        s = d * d;
    }
    red[tid] = s; __syncthreads();
    for (int off = 128; off > 0; off >>= 1) {
        if (tid < off) red[tid] += red[tid + off];
        __syncthreads();
    }
    if (tid == 0) partials[blockIdx.x] = red[0];
}

// ------- fused GEMM: 8 waves/block, 16-row wave tile, 11-deep af prefetch bank --------------
__global__ __launch_bounds__(512, 4) void k_gemm(
        const float* __restrict__ noise, const float* __restrict__ F,
        const float* __restrict__ llev, const short* __restrict__ W1T,
        const float* __restrict__ b1, const short* __restrict__ W2T,
        const float* __restrict__ b2, const float* __restrict__ S1,
        const float* __restrict__ partials, const int* __restrict__ lvp,
        float* __restrict__ out, float* __restrict__ labels, float* __restrict__ loss) {
    __shared__ __align__(16) short hlds[64][360];   // 46080 B (cols 336..351 exact zeros)
    __shared__ __align__(16) float Flds[448];
    __shared__ __align__(16) float Llds[64];
    __shared__ __align__(16) float b1lds[352];
    __shared__ __align__(16) float S1lds[352];      // total 50944 B

    int t = threadIdx.x, w = t >> 6, l = t & 63;
    int lm = l & 15, lq = l >> 4;
    long n0 = (long)blockIdx.x * 64;

    // loss final (block 0, wave 7)
    if (blockIdx.x == 0 && w == 7) {
        float s = partials[l] + partials[l + 64] + partials[l + 128];
        if (l < 4) s += partials[l + 192];
#pragma unroll
        for (int off = 32; off > 0; off >>= 1) s += __shfl_down(s, off, 64);
        if (l == 0) loss[0] = s / (float)(T_LEN - 2) * (float)lvp[0];
    }

    // stage Flds / Llds / b1lds / S1lds (512 threads -> one shot)
    if (t < 112)      *(f32x4*)&Flds[t * 4] = *(const f32x4*)&F[n0 + t * 4];
    else if (t < 128) *(f32x4*)&Llds[(t - 112) * 4] = *(const f32x4*)&llev[n0 + W_IN + (t - 112) * 4];
    else if (t < 216) {
        int i4 = (t - 128) * 4;
        f32x4 v = (f32x4){0.f, 0.f, 0.f, 0.f};
        if (i4 < W_IN) v = *(const f32x4*)&b1[i4];
        *(f32x4*)&b1lds[i4] = v;
    } else if (t < 304) {
        int i4 = (t - 216) * 4;
        *(f32x4*)&S1lds[i4] = *(const f32x4*)&S1[i4];
    }

    int rbase = (w >> 1) * 16;     // 0,16,32,48  (wave pairs share a row group)
    int jbase = (w & 1) * 176;     // j half
    long an0 = n0 + rbase + lm; if (an0 > N_ROWS - 2) an0 = N_ROWS - 2;
    const float* nr0 = noise + an0 * W_IN + lq * 8;

    // noise prefetch 1-deep
    f32x4 nc0 = *(const f32x4*)&nr0[0], nc1 = *(const f32x4*)&nr0[4];

    f32x4 acc[11];
#pragma unroll
    for (int c = 0; c < 11; ++c) acc[c] = (f32x4){0.f, 0.f, 0.f, 0.f};

    const short* w1row = &W1T[(jbase + lm) * 352 + lq * 8];
#define LDW(CT, KS) (*(const s16x8*)&w1row[(CT) * 5632 + (KS) * 32])
    // 11-deep af bank: each reg reloaded for ks+1 right after its MFMA consumes it
    s16x8 af0 = LDW(0,0), af1 = LDW(1,0), af2 = LDW(2,0), af3 = LDW(3,0), af4 = LDW(4,0),
          af5 = LDW(5,0), af6 = LDW(6,0), af7 = LDW(7,0), af8 = LDW(8,0), af9 = LDW(9,0),
          af10 = LDW(10,0);

    __syncthreads();

#define MM(CT, AF) acc[CT] = __builtin_amdgcn_mfma_f32_16x16x32_bf16(AF, bf0, acc[CT], 0, 0, 0);

#define KSTEP(KS) { \
    s16x8 bf0; \
    { int fb = rbase + lm + (KS) * 32 + lq * 8; \
      int* b0i = (int*)&bf0; \
      b0i[0] = bfpk(Flds[fb+0] + nc0[0], Flds[fb+1] + nc0[1]); \
      b0i[1] = bfpk(Flds[fb+2] + nc0[2], Flds[fb+3] + nc0[3]); \
      b0i[2] = bfpk(Flds[fb+4] + nc1[0], Flds[fb+5] + nc1[1]); \
      b0i[3] = bfpk(Flds[fb+6] + nc1[2], Flds[fb+7] + nc1[3]); } \
    if ((KS) < 10) { \
      nc0 = *(const f32x4*)&nr0[((KS)+1)*32]; \
      nc1 = *(const f32x4*)&nr0[((KS)+1)*32+4]; \
    } \
    MM(0, af0)   if ((KS) < 10) af0  = LDW(0,  (KS)+1); \
    MM(1, af1)   if ((KS) < 10) af1  = LDW(1,  (KS)+1); \
    MM(2, af2)   if ((KS) < 10) af2  = LDW(2,  (KS)+1); \
    MM(3, af3)   if ((KS) < 10) af3  = LDW(3,  (KS)+1); \
    MM(4, af4)   if ((KS) < 10) af4  = LDW(4,  (KS)+1); \
    MM(5, af5)   if ((KS) < 10) af5  = LDW(5,  (KS)+1); \
    MM(6, af6)   if ((KS) < 10) af6  = LDW(6,  (KS)+1); \
    MM(7, af7)   if ((KS) < 10) af7  = LDW(7,  (KS)+1); \
    MM(8, af8)   if ((KS) < 10) af8  = LDW(8,  (KS)+1); \
    MM(9, af9)   if ((KS) < 10) af9  = LDW(9,  (KS)+1); \
    MM(10, af10) if ((KS) < 10) af10 = LDW(10, (KS)+1); \
}

    KSTEP(0) KSTEP(1) KSTEP(2) KSTEP(3) KSTEP(4) KSTEP(5)
    KSTEP(6) KSTEP(7) KSTEP(8) KSTEP(9) KSTEP(10)
#undef KSTEP
#undef MM
#undef LDW

    // epilogue 1: h = tanh(acc + b1 - lv*S1) -> hlds
    float lv0 = Llds[rbase + lm];
#pragma unroll
    for (int ct = 0; ct < 11; ++ct) {
        f32x4 b1q = *(f32x4*)&b1lds[jbase + ct * 16 + lq * 4];
        f32x4 s1q = *(f32x4*)&S1lds[jbase + ct * 16 + lq * 4];
        int2 p0;
        p0.x = bfpk(fast_tanh(fmaf(-lv0, s1q[0], acc[ct][0] + b1q[0])),
                    fast_tanh(fmaf(-lv0, s1q[1], acc[ct][1] + b1q[1])));
        p0.y = bfpk(fast_tanh(fmaf(-lv0, s1q[2], acc[ct][2] + b1q[2])),
                    fast_tanh(fmaf(-lv0, s1q[3], acc[ct][3] + b1q[3])));
        *(int2*)&hlds[rbase + lm][jbase + ct * 16 + lq * 4] = p0;
    }
    __syncthreads();

    if (w < 4) {
        // gemm2: rows w*16..w*16+15; out stores
        f32x4 a2[3];
        a2[0] = (f32x4){0,0,0,0}; a2[1] = (f32x4){0,0,0,0}; a2[2] = (f32x4){0,0,0,0};
#pragma unroll
        for (int ks = 0; ks < 11; ++ks) {
            s16x8 hf = *(s16x8*)&hlds[w * 16 + lm][ks * 32 + lq * 8];
#pragma unroll
            for (int ct = 0; ct < 3; ++ct) {
                s16x8 bf2 = *(const s16x8*)&W2T[(ct * 16 + lm) * 360 + ks * 32 + lq * 8];
                a2[ct] = __builtin_amdgcn_mfma_f32_16x16x32_bf16(hf, bf2, a2[ct], 0, 0, 0);
            }
        }
        int rloc = w * 16 + lq * 4;
#pragma unroll
        for (int ct = 0; ct < 3; ++ct) {
            float b2v = b2[ct * 16 + lm];
#pragma unroll
            for (int r = 0; r < 4; ++r) {
                long row = n0 + rloc + r;
                if (row < N_ROWS) out[row * O_OUT + ct * 16 + lm] = a2[ct][r] + b2v;
            }
        }
    } else {
        // labels: rows (w-4)*16 .. +15; 4 lanes per row, 12 cols each
        int rb2 = (w - 4) * 16;
        int lrow = l >> 2, cbase = (l & 3) * 12;
        long row = n0 + rb2 + lrow;
        if (row < N_ROWS) {
            float fl = -Llds[rb2 + lrow];
            const float* fp = &Flds[rb2 + lrow + W_IN + cbase];
            float* lp = &labels[row * O_OUT + cbase];
#pragma unroll
            for (int i = 0; i < 12; ++i) lp[i] = fp[i] + fl;
        }
    }
}

extern "C" void kernel_launch(void* const* d_in, const int* in_sizes, int n_in,
                              void* d_out, int out_size, void* d_ws, size_t ws_size,
                              hipStream_t stream) {
    const float* x         = (const float*)d_in[0];
    const float* noise     = (const float*)d_in[1];
    const float* level_sc  = (const float*)d_in[2];
    const float* seas_sc   = (const float*)d_in[3];
    const float* init_seas = (const float*)d_in[4];
    const float* W1        = (const float*)d_in[5];
    const float* b1        = (const float*)d_in[6];
    const float* W2        = (const float*)d_in[7];
    const float* b2        = (const float*)d_in[8];
    const int*   lvp       = (const int*)d_in[11];

    float* out    = (float*)d_out;
    float* labels = out + (long)N_ROWS * O_OUT;
    float* loss   = labels + (long)N_ROWS * O_OUT;

    float* wsf      = (float*)d_ws;
    float* lw       = wsf;                 // 2*50000 packed {level,w} (reserve 100096)
    float* seasinit = wsf + 100096;        // 169 (reserve 192)
    float* F        = wsf + 100288;        // 50000 (reserve 50176)
    float* llev     = wsf + 150464;        // 50000 (reserve 50048)
    float* partials = wsf + 200512;        // 196 (reserve 256)
    float* S1f      = wsf + 200768;        // 352 (reserve 384)
    short* W1T      = (short*)(wsf + 201152);   // 352*352 bf16 (zero-padded)
    short* W2T      = W1T + 352 * 352;          // 48*360 bf16

    k_preconvert<<<554, 256, 0, stream>>>(W1, W2, W1T, W2T, S1f);
    k_scan<<<1, 64, 0, stream>>>(x, level_sc, seas_sc, init_seas, lw, seasinit);
    k_logs<<<196, 256, 0, stream>>>(x, lw, seasinit, F, llev, partials);
    k_gemm<<<NBLK, 512, 0, stream>>>(noise, F, llev, W1T, b1, W2T, b2, S1f,
                                     partials, lvp, out, labels, loss);
}